// Round 4
// baseline (55.595 us; speedup 1.0000x reference)
//
#include <hip/hip_runtime.h>

// ---- G(3,0,1) PGA tables, generated at compile time via bitmask blades ----
namespace ga {

// Blade order matches the Python reference:
// idx : 0=1, 1=e0, 2=e1, 3=e2, 4=e3, 5=e01, 6=e02, 7=e03, 8=e12, 9=e13,
//       10=e23, 11=e012, 12=e013, 13=e023, 14=e123, 15=e0123
constexpr unsigned MASKS[16] = {0u, 1u, 2u, 4u, 8u,
                                3u, 5u, 9u, 6u, 10u, 12u,
                                7u, 11u, 13u, 14u, 15u};

constexpr int idx_of_mask(unsigned m) {
  for (int i = 0; i < 16; ++i)
    if (MASKS[i] == m) return i;
  return -1;
}

constexpr int popc4(unsigned x) {
  int c = 0;
  for (int i = 0; i < 4; ++i) c += (x >> i) & 1u;
  return c;
}

// sign to sort concatenation [A..., B...]: (-1)^{#(a in A, b in B : a > b)}
constexpr int reorder_sign(unsigned a, unsigned b) {
  int cnt = 0;
  for (int i = 0; i < 4; ++i)
    if ((a >> i) & 1u) cnt += popc4(b & ((1u << i) - 1u));
  return (cnt & 1) ? -1 : 1;
}

struct Tab {
  float gp_s[16][16];
  int   gp_k[16][16];
  float jn_s[16][16];
  int   jn_k[16][16];
};

constexpr Tab make_tab() {
  Tab t{};
  float msign[16] = {};
  for (int i = 0; i < 16; ++i) {
    unsigned a = MASKS[i];
    msign[i] = (float)reorder_sign(a, (~a) & 0xFu);
  }
  for (int i = 0; i < 16; ++i) {
    for (int j = 0; j < 16; ++j) {
      unsigned A = MASKS[i], B = MASKS[j];
      if (A & B & 1u) {  // e0 repeats -> 0 (degenerate metric)
        t.gp_s[i][j] = 0.0f; t.gp_k[i][j] = 0;
      } else {
        t.gp_s[i][j] = (float)reorder_sign(A, B);
        t.gp_k[i][j] = idx_of_mask(A ^ B);
      }
      unsigned Ac = (~A) & 0xFu, Bc = (~B) & 0xFu;
      if (Ac & Bc) {
        t.jn_s[i][j] = 0.0f; t.jn_k[i][j] = 0;
      } else {
        unsigned Cc = Ac | Bc;
        int k = idx_of_mask((~Cc) & 0xFu);
        float s = (float)reorder_sign(Ac, Bc)
                * msign[i] * msign[j]
                * msign[k];
        t.jn_s[i][j] = s; t.jn_k[i][j] = k;
      }
    }
  }
  return t;
}

constexpr Tab TAB = make_tab();

} // namespace ga

typedef float f32x4 __attribute__((ext_vector_type(4)));

__global__ __launch_bounds__(256)
void mv_bilinear_kernel(const float4* __restrict__ x4,
                        const float4* __restrict__ y4,
                        const f32x4* __restrict__ ref4,
                        float4*       __restrict__ o4,
                        int npts) {
  // 256 points/block * 8 float4 out = 32 KB staging
  __shared__ f32x4 sout[2048];

  const int t = threadIdx.x;
  const int pbase = blockIdx.x * 256;
  const int p = pbase + t;
  const bool act = p < npts;

  float xv[16], yv[16];
  float r = 0.0f;
  if (act) {
    float4 a = x4[p * 4 + 0], b = x4[p * 4 + 1],
           c = x4[p * 4 + 2], d = x4[p * 4 + 3];
    xv[0]=a.x; xv[1]=a.y; xv[2]=a.z; xv[3]=a.w;
    xv[4]=b.x; xv[5]=b.y; xv[6]=b.z; xv[7]=b.w;
    xv[8]=c.x; xv[9]=c.y; xv[10]=c.z; xv[11]=c.w;
    xv[12]=d.x; xv[13]=d.y; xv[14]=d.z; xv[15]=d.w;
    a = y4[p * 4 + 0]; b = y4[p * 4 + 1];
    c = y4[p * 4 + 2]; d = y4[p * 4 + 3];
    yv[0]=a.x; yv[1]=a.y; yv[2]=a.z; yv[3]=a.w;
    yv[4]=b.x; yv[5]=b.y; yv[6]=b.z; yv[7]=b.w;
    yv[8]=c.x; yv[9]=c.y; yv[10]=c.z; yv[11]=c.w;
    yv[12]=d.x; yv[13]=d.y; yv[14]=d.z; yv[15]=d.w;
    // ref: only channel 15 is used (1/16 of the tensor). Nontemporal load
    // so the 64 MiB ref stream does NOT allocate in L2/MALL -> leaves the
    // Infinity Cache to the fully-reused 128 MiB x+y set.
    f32x4 rv = __builtin_nontemporal_load(&ref4[p * 4 + 3]);
    r = rv.w;
  } else {
    #pragma unroll
    for (int k = 0; k < 16; ++k) { xv[k] = 0.0f; yv[k] = 0.0f; }
  }

  float gp[16], jn[16];
  #pragma unroll
  for (int k = 0; k < 16; ++k) { gp[k] = 0.0f; jn[k] = 0.0f; }

  // Fully unrolled sparse bilinear: all table entries fold to literals.
  #pragma unroll
  for (int i = 0; i < 16; ++i) {
    #pragma unroll
    for (int j = 0; j < 16; ++j) {
      const float gs = ga::TAB.gp_s[i][j];
      const float js = ga::TAB.jn_s[i][j];
      if (gs != 0.0f || js != 0.0f) {
        const float prod = xv[i] * yv[j];
        if (gs != 0.0f) {
          const int k = ga::TAB.gp_k[i][j];
          gp[k] = (gs > 0.0f) ? (gp[k] + prod) : (gp[k] - prod);
        }
        if (js != 0.0f) {
          const int k = ga::TAB.jn_k[i][j];
          jn[k] = (js > 0.0f) ? (jn[k] + prod) : (jn[k] - prod);
        }
      }
    }
  }

  // Stage this point's 8 output float4s into LDS, XOR-swizzled on the
  // float4 index (0 bank conflicts measured in rounds 2-3).
  {
    f32x4 v[8];
    v[0] = (f32x4){gp[0],  gp[1],  gp[2],  gp[3]};
    v[1] = (f32x4){gp[4],  gp[5],  gp[6],  gp[7]};
    v[2] = (f32x4){gp[8],  gp[9],  gp[10], gp[11]};
    v[3] = (f32x4){gp[12], gp[13], gp[14], gp[15]};
    v[4] = (f32x4){r*jn[0],  r*jn[1],  r*jn[2],  r*jn[3]};
    v[5] = (f32x4){r*jn[4],  r*jn[5],  r*jn[6],  r*jn[7]};
    v[6] = (f32x4){r*jn[8],  r*jn[9],  r*jn[10], r*jn[11]};
    v[7] = (f32x4){r*jn[12], r*jn[13], r*jn[14], r*jn[15]};
    #pragma unroll
    for (int c = 0; c < 8; ++c)
      sout[t * 8 + (c ^ (t & 7))] = v[c];
  }
  __syncthreads();

  // Coalesced, nontemporal writeback: each store instruction covers a
  // contiguous 1 KiB (8 full 128B lines), each line written exactly once,
  // bypassing cache allocation (write-once stream).
  const size_t gbase = (size_t)pbase * 8;
  #pragma unroll
  for (int k = 0; k < 8; ++k) {
    const int f = t + 256 * k;            // float4 index within block tile
    const int pl = f >> 3;                 // local point
    const int c  = f & 7;                  // float4 slot within point
    if (pbase + pl < npts) {
      f32x4 v = sout[pl * 8 + (c ^ (pl & 7))];
      __builtin_nontemporal_store(v, (f32x4*)&o4[gbase + f]);
    }
  }
}

extern "C" void kernel_launch(void* const* d_in, const int* in_sizes, int n_in,
                              void* d_out, int out_size, void* d_ws, size_t ws_size,
                              hipStream_t stream) {
  const float4* x4  = (const float4*)d_in[0];
  const float4* y4  = (const float4*)d_in[1];
  const f32x4*  ref4 = (const f32x4*)d_in[2];
  float4* o4 = (float4*)d_out;

  const int npts = in_sizes[0] / 16;  // B*T multivectors
  const int block = 256;
  const int grid = (npts + block - 1) / block;
  mv_bilinear_kernel<<<grid, block, 0, stream>>>(x4, y4, ref4, o4, npts);
}

// Round 5
// 53.599 us; speedup vs baseline: 1.0372x; 1.0372x over previous
//
#include <hip/hip_runtime.h>

// ---- G(3,0,1) PGA tables, generated at compile time via bitmask blades ----
namespace ga {

// Blade order matches the Python reference:
// idx : 0=1, 1=e0, 2=e1, 3=e2, 4=e3, 5=e01, 6=e02, 7=e03, 8=e12, 9=e13,
//       10=e23, 11=e012, 12=e013, 13=e023, 14=e123, 15=e0123
constexpr unsigned MASKS[16] = {0u, 1u, 2u, 4u, 8u,
                                3u, 5u, 9u, 6u, 10u, 12u,
                                7u, 11u, 13u, 14u, 15u};

constexpr int idx_of_mask(unsigned m) {
  for (int i = 0; i < 16; ++i)
    if (MASKS[i] == m) return i;
  return -1;
}

constexpr int popc4(unsigned x) {
  int c = 0;
  for (int i = 0; i < 4; ++i) c += (x >> i) & 1u;
  return c;
}

// sign to sort concatenation [A..., B...]: (-1)^{#(a in A, b in B : a > b)}
constexpr int reorder_sign(unsigned a, unsigned b) {
  int cnt = 0;
  for (int i = 0; i < 4; ++i)
    if ((a >> i) & 1u) cnt += popc4(b & ((1u << i) - 1u));
  return (cnt & 1) ? -1 : 1;
}

struct Tab {
  float gp_s[16][16];
  int   gp_k[16][16];
  float jn_s[16][16];
  int   jn_k[16][16];
};

constexpr Tab make_tab() {
  Tab t{};
  float msign[16] = {};
  for (int i = 0; i < 16; ++i) {
    unsigned a = MASKS[i];
    msign[i] = (float)reorder_sign(a, (~a) & 0xFu);
  }
  for (int i = 0; i < 16; ++i) {
    for (int j = 0; j < 16; ++j) {
      unsigned A = MASKS[i], B = MASKS[j];
      if (A & B & 1u) {  // e0 repeats -> 0 (degenerate metric)
        t.gp_s[i][j] = 0.0f; t.gp_k[i][j] = 0;
      } else {
        t.gp_s[i][j] = (float)reorder_sign(A, B);
        t.gp_k[i][j] = idx_of_mask(A ^ B);
      }
      unsigned Ac = (~A) & 0xFu, Bc = (~B) & 0xFu;
      if (Ac & Bc) {
        t.jn_s[i][j] = 0.0f; t.jn_k[i][j] = 0;
      } else {
        unsigned Cc = Ac | Bc;
        int k = idx_of_mask((~Cc) & 0xFu);
        float s = (float)reorder_sign(Ac, Bc)
                * msign[i] * msign[j]
                * msign[k];
        t.jn_s[i][j] = s; t.jn_k[i][j] = k;
      }
    }
  }
  return t;
}

constexpr Tab TAB = make_tab();

} // namespace ga

typedef float f32x4 __attribute__((ext_vector_type(4)));

__device__ __forceinline__ void gload_lds16(const f32x4* gsrc, f32x4* ldst) {
  __builtin_amdgcn_global_load_lds(
      (const __attribute__((address_space(1))) void*)gsrc,
      (__attribute__((address_space(3))) void*)ldst, 16, 0, 0);
}

// Shared sparse-bilinear core (fully unrolled; table entries fold to literals)
__device__ __forceinline__ void mv_core(const float xv[16], const float yv[16],
                                        float gp[16], float jn[16]) {
  #pragma unroll
  for (int k = 0; k < 16; ++k) { gp[k] = 0.0f; jn[k] = 0.0f; }
  #pragma unroll
  for (int i = 0; i < 16; ++i) {
    #pragma unroll
    for (int j = 0; j < 16; ++j) {
      const float gs = ga::TAB.gp_s[i][j];
      const float js = ga::TAB.jn_s[i][j];
      if (gs != 0.0f || js != 0.0f) {
        const float prod = xv[i] * yv[j];
        if (gs != 0.0f) {
          const int k = ga::TAB.gp_k[i][j];
          gp[k] = (gs > 0.0f) ? (gp[k] + prod) : (gp[k] - prod);
        }
        if (js != 0.0f) {
          const int k = ga::TAB.jn_k[i][j];
          jn[k] = (js > 0.0f) ? (jn[k] + prod) : (jn[k] - prod);
        }
      }
    }
  }
}

// Main kernel: full 256-point tiles only (npts % 256 handled by tail kernel).
__global__ __launch_bounds__(256)
void mv_bilinear_kernel(const f32x4* __restrict__ x4,
                        const f32x4* __restrict__ y4,
                        const f32x4* __restrict__ ref4,
                        f32x4*       __restrict__ o4) {
  // 32 KB, reused: input phase = x[0..1024) + y[1024..2048); output phase = out tile
  __shared__ f32x4 lds[2048];

  const int t  = threadIdx.x;
  const int w  = t >> 6;          // wave id
  const int ti = t & 63;          // lane
  const int pbase = blockIdx.x * 256;

  // Involutive source swizzle (s ^= (s>>3)&3), within each 1KB window:
  // keeps each global_load_lds covering exactly 8 full 128B lines, while the
  // per-point LDS read lands on the 8-row x 8-col conflict-floor pattern.
  const int lsw = ti ^ ((ti >> 3) & 3);

  // Stage x,y tiles direct-to-LDS: 8 fully-coalesced 1KB load instructions.
  const size_t gofs = (size_t)pbase * 4 + w * 256;
  #pragma unroll
  for (int k = 0; k < 4; ++k)
    gload_lds16(x4 + gofs + k * 64 + lsw, &lds[w * 256 + k * 64]);
  #pragma unroll
  for (int k = 0; k < 4; ++k)
    gload_lds16(y4 + gofs + k * 64 + lsw, &lds[1024 + w * 256 + k * 64]);

  // ref: only channel 15 used; 16B strided load (compulsory traffic).
  const float r = ((const float*)ref4)[(size_t)(pbase + t) * 16 + 15];

  // global_load_lds -> ds_read dependency is NOT compiler-tracked: fence it.
  __asm__ volatile("s_waitcnt vmcnt(0)" ::: "memory");
  __builtin_amdgcn_sched_barrier(0);

  // Each wave reads only its own staged region -> wave-local, no barrier yet.
  float xv[16], yv[16];
  const int vsw = (ti >> 1) & 3;
  #pragma unroll
  for (int c = 0; c < 4; ++c) {
    f32x4 a = lds[w * 256 + 4 * ti + (c ^ vsw)];
    xv[4*c+0] = a[0]; xv[4*c+1] = a[1]; xv[4*c+2] = a[2]; xv[4*c+3] = a[3];
  }
  #pragma unroll
  for (int c = 0; c < 4; ++c) {
    f32x4 a = lds[1024 + w * 256 + 4 * ti + (c ^ vsw)];
    yv[4*c+0] = a[0]; yv[4*c+1] = a[1]; yv[4*c+2] = a[2]; yv[4*c+3] = a[3];
  }
  __syncthreads();  // all input reads done before the out-tile overwrites LDS

  float gp[16], jn[16];
  mv_core(xv, yv, gp, jn);

  // Stage output (XOR-swizzled; measured 0 bank conflicts in rounds 2-4).
  {
    f32x4 v[8];
    v[0] = (f32x4){gp[0],  gp[1],  gp[2],  gp[3]};
    v[1] = (f32x4){gp[4],  gp[5],  gp[6],  gp[7]};
    v[2] = (f32x4){gp[8],  gp[9],  gp[10], gp[11]};
    v[3] = (f32x4){gp[12], gp[13], gp[14], gp[15]};
    v[4] = (f32x4){r*jn[0],  r*jn[1],  r*jn[2],  r*jn[3]};
    v[5] = (f32x4){r*jn[4],  r*jn[5],  r*jn[6],  r*jn[7]};
    v[6] = (f32x4){r*jn[8],  r*jn[9],  r*jn[10], r*jn[11]};
    v[7] = (f32x4){r*jn[12], r*jn[13], r*jn[14], r*jn[15]};
    #pragma unroll
    for (int c = 0; c < 8; ++c)
      lds[t * 8 + (c ^ (t & 7))] = v[c];
  }
  __syncthreads();

  // Coalesced NT writeback: 1KB per instruction, every line written once.
  const size_t gbase = (size_t)pbase * 8;
  #pragma unroll
  for (int k = 0; k < 8; ++k) {
    const int f  = t + 256 * k;
    const int pl = f >> 3;
    const int c  = f & 7;
    f32x4 v = lds[pl * 8 + (c ^ (pl & 7))];
    __builtin_nontemporal_store(v, &o4[gbase + f]);
  }
}

// Tail kernel for the (unused in this harness) npts % 256 != 0 remainder.
__global__ __launch_bounds__(256)
void mv_bilinear_tail(const float4* __restrict__ x4,
                      const float4* __restrict__ y4,
                      const float*  __restrict__ ref,
                      float4*       __restrict__ o4,
                      int pstart, int npts) {
  const int p = pstart + threadIdx.x;
  if (p >= npts) return;
  float xv[16], yv[16];
  float4 a;
  #pragma unroll
  for (int c = 0; c < 4; ++c) {
    a = x4[(size_t)p * 4 + c];
    xv[4*c]=a.x; xv[4*c+1]=a.y; xv[4*c+2]=a.z; xv[4*c+3]=a.w;
  }
  #pragma unroll
  for (int c = 0; c < 4; ++c) {
    a = y4[(size_t)p * 4 + c];
    yv[4*c]=a.x; yv[4*c+1]=a.y; yv[4*c+2]=a.z; yv[4*c+3]=a.w;
  }
  const float r = ref[(size_t)p * 16 + 15];
  float gp[16], jn[16];
  mv_core(xv, yv, gp, jn);
  float4* o = o4 + (size_t)p * 8;
  o[0] = make_float4(gp[0],  gp[1],  gp[2],  gp[3]);
  o[1] = make_float4(gp[4],  gp[5],  gp[6],  gp[7]);
  o[2] = make_float4(gp[8],  gp[9],  gp[10], gp[11]);
  o[3] = make_float4(gp[12], gp[13], gp[14], gp[15]);
  o[4] = make_float4(r*jn[0],  r*jn[1],  r*jn[2],  r*jn[3]);
  o[5] = make_float4(r*jn[4],  r*jn[5],  r*jn[6],  r*jn[7]);
  o[6] = make_float4(r*jn[8],  r*jn[9],  r*jn[10], r*jn[11]);
  o[7] = make_float4(r*jn[12], r*jn[13], r*jn[14], r*jn[15]);
}

extern "C" void kernel_launch(void* const* d_in, const int* in_sizes, int n_in,
                              void* d_out, int out_size, void* d_ws, size_t ws_size,
                              hipStream_t stream) {
  const int npts   = in_sizes[0] / 16;  // B*T multivectors
  const int ntiles = npts / 256;
  const int tail   = npts - ntiles * 256;

  if (ntiles > 0) {
    mv_bilinear_kernel<<<ntiles, 256, 0, stream>>>(
        (const f32x4*)d_in[0], (const f32x4*)d_in[1],
        (const f32x4*)d_in[2], (f32x4*)d_out);
  }
  if (tail > 0) {
    mv_bilinear_tail<<<1, 256, 0, stream>>>(
        (const float4*)d_in[0], (const float4*)d_in[1],
        (const float*)d_in[2], (float4*)d_out, ntiles * 256, npts);
  }
}